// Round 1
// baseline (617.349 us; speedup 1.0000x reference)
//
#include <hip/hip_runtime.h>
#include <stdint.h>

typedef short short8 __attribute__((ext_vector_type(8)));
typedef float f32x4 __attribute__((ext_vector_type(4)));
typedef unsigned short ushort4v __attribute__((ext_vector_type(4)));

// f32 -> bf16 round-to-nearest-even
__device__ __forceinline__ unsigned short f2bf(float f) {
  union { float f; unsigned u; } v; v.f = f;
  unsigned r = v.u + 0x7fffu + ((v.u >> 16) & 1u);
  return (unsigned short)(r >> 16);
}

// async global->LDS, 16B per lane; lds dst must be wave-uniform (lane*16 auto)
__device__ __forceinline__ void gld_lds16(const void* g, void* l) {
  __builtin_amdgcn_global_load_lds((const __attribute__((address_space(1))) void*)g,
                                   (__attribute__((address_space(3))) void*)l, 16, 0, 0);
}

// ---------------- RoPE + cast to bf16 (query,key) ----------------
// 1,048,576 threads: idx -> (b,t,h, 4-elem group of lower 32 dims)
__global__ void rope_kernel(const float* __restrict__ q, const float* __restrict__ k,
                            const float* __restrict__ cs, const float* __restrict__ sn,
                            unsigned short* __restrict__ qo, unsigned short* __restrict__ ko) {
  const int idx = blockIdx.x * 256 + threadIdx.x;
  const int p   = idx & 7;            // which 4-group within [0,32)
  const int bth = idx >> 3;           // b*16384 + t*16 + h
  const int t   = (bth >> 4) & 1023;
  const size_t base = (size_t)bth * 64;
  const int dd0 = p * 4;

  const float4 x0 = *(const float4*)(q + base + dd0);
  const float4 x1 = *(const float4*)(q + base + dd0 + 32);
  const float4 y0 = *(const float4*)(k + base + dd0);
  const float4 y1 = *(const float4*)(k + base + dd0 + 32);
  const float4 c0 = *(const float4*)(cs + t * 64 + dd0);
  const float4 c1 = *(const float4*)(cs + t * 64 + dd0 + 32);
  const float4 s0 = *(const float4*)(sn + t * 64 + dd0);
  const float4 s1 = *(const float4*)(sn + t * 64 + dd0 + 32);

  ushort4v qlo, qhi, klo, khi;
  qlo[0]=f2bf(x0.x*c0.x - x1.x*s0.x); qlo[1]=f2bf(x0.y*c0.y - x1.y*s0.y);
  qlo[2]=f2bf(x0.z*c0.z - x1.z*s0.z); qlo[3]=f2bf(x0.w*c0.w - x1.w*s0.w);
  qhi[0]=f2bf(x1.x*c1.x + x0.x*s1.x); qhi[1]=f2bf(x1.y*c1.y + x0.y*s1.y);
  qhi[2]=f2bf(x1.z*c1.z + x0.z*s1.z); qhi[3]=f2bf(x1.w*c1.w + x0.w*s1.w);
  klo[0]=f2bf(y0.x*c0.x - y1.x*s0.x); klo[1]=f2bf(y0.y*c0.y - y1.y*s0.y);
  klo[2]=f2bf(y0.z*c0.z - y1.z*s0.z); klo[3]=f2bf(y0.w*c0.w - y1.w*s0.w);
  khi[0]=f2bf(y1.x*c1.x + y0.x*s1.x); khi[1]=f2bf(y1.y*c1.y + y0.y*s1.y);
  khi[2]=f2bf(y1.z*c1.z + y0.z*s1.z); khi[3]=f2bf(y1.w*c1.w + y0.w*s1.w);

  *(ushort4v*)(qo + base + dd0)      = qlo;
  *(ushort4v*)(qo + base + dd0 + 32) = qhi;
  *(ushort4v*)(ko + base + dd0)      = klo;
  *(ushort4v*)(ko + base + dd0 + 32) = khi;
}

// ---------------- plain f32 -> bf16 cast ----------------
__global__ void cast_kernel(const float* __restrict__ src, unsigned short* __restrict__ dst, int n4) {
  const int i = blockIdx.x * 256 + threadIdx.x;
  if (i < n4) {
    const float4 v = *(const float4*)(src + (size_t)i * 4);
    ushort4v o;
    o[0]=f2bf(v.x); o[1]=f2bf(v.y); o[2]=f2bf(v.z); o[3]=f2bf(v.w);
    *(ushort4v*)(dst + (size_t)i * 4) = o;
  }
}

// ---------------- bf16 GEMM, C[m,n] = sum_k A[m,k]*B[n,k] + bias[n] ----------------
// M=8192, N=K=1024. 128x128 tile, BK=64. MODE 0: f32 row-major out.
// MODE 1: bf16 out permuted (b,h,t,d). MODE 2: bf16 out transposed (b,h,d,t).
template <int MODE>
__global__ __launch_bounds__(256, 2) void gemm_bt(
    const unsigned short* __restrict__ A, const unsigned short* __restrict__ Bw,
    const float* __restrict__ bias, void* __restrict__ C) {
  constexpr int K = 1024, N = 1024;
  const int tid = threadIdx.x;
  const int wave = tid >> 6, lane = tid & 63;
  const int m0 = blockIdx.x * 128, n0 = blockIdx.y * 128;
  __shared__ unsigned short Asm[128 * 64];
  __shared__ unsigned short Bsm[128 * 64];
  f32x4 acc[4][4] = {};
  const int wr = (wave >> 1) * 64, wc = (wave & 1) * 64;
  const int ld_row = lane >> 3, ld_col = (lane & 7) * 8;
  const int fr = lane & 15, fk = (lane >> 4) * 8;

  for (int k0 = 0; k0 < K; k0 += 64) {
#pragma unroll
    for (int j = 0; j < 4; ++j) {
      const int c = j * 4 + wave;
      gld_lds16(A  + (size_t)(m0 + 8 * c + ld_row) * K + k0 + ld_col, &Asm[c * 512]);
      gld_lds16(Bw + (size_t)(n0 + 8 * c + ld_row) * K + k0 + ld_col, &Bsm[c * 512]);
    }
    __syncthreads();
#pragma unroll
    for (int ks = 0; ks < 2; ++ks) {
      short8 af[4], bf[4];
#pragma unroll
      for (int i = 0; i < 4; ++i)
        af[i] = *(const short8*)&Asm[(wr + i * 16 + fr) * 64 + ks * 32 + fk];
#pragma unroll
      for (int i = 0; i < 4; ++i)
        bf[i] = *(const short8*)&Bsm[(wc + i * 16 + fr) * 64 + ks * 32 + fk];
#pragma unroll
      for (int i = 0; i < 4; ++i)
#pragma unroll
        for (int j = 0; j < 4; ++j)
          acc[i][j] = __builtin_amdgcn_mfma_f32_16x16x32_bf16(af[i], bf[j], acc[i][j], 0, 0, 0);
    }
    __syncthreads();
  }

#pragma unroll
  for (int i = 0; i < 4; ++i) {
    const int row_base = m0 + wr + i * 16 + (lane >> 4) * 4;
#pragma unroll
    for (int j = 0; j < 4; ++j) {
      const int col = n0 + wc + j * 16 + fr;
      const float bval = bias[col];
      if (MODE == 0) {
        float* Co = (float*)C;
#pragma unroll
        for (int r = 0; r < 4; ++r)
          Co[(size_t)(row_base + r) * N + col] = acc[i][j][r] + bval;
      } else if (MODE == 1) {
        unsigned short* Co = (unsigned short*)C;
        const int h_i = col >> 6, dd = col & 63;
#pragma unroll
        for (int r = 0; r < 4; ++r) {
          const int row = row_base + r;
          const int b_i = row >> 10, t_i = row & 1023;
          Co[((size_t)(b_i * 16 + h_i) * 1024 + t_i) * 64 + dd] = f2bf(acc[i][j][r] + bval);
        }
      } else {
        unsigned short* Co = (unsigned short*)C;
        const int h_i = col >> 6, dd = col & 63;
        const int b_i = row_base >> 10, t_i = row_base & 1023;
        ushort4v pk;
        pk[0] = f2bf(acc[i][j][0] + bval); pk[1] = f2bf(acc[i][j][1] + bval);
        pk[2] = f2bf(acc[i][j][2] + bval); pk[3] = f2bf(acc[i][j][3] + bval);
        *(ushort4v*)&Co[((size_t)(b_i * 16 + h_i) * 64 + dd) * 1024 + t_i] = pk;
      }
    }
  }
}

// ---------------- flash attention ----------------
// grid: (8 q-tiles, 128 bh). Q tile 128 rows (32/wave), K/V tiles 128.
// Qp,Kp: (b,h,t,d) bf16. Vt: (b,h,d,t) bf16. O: (b,t,f) bf16.
__global__ __launch_bounds__(256, 2) void flash_attn(
    const unsigned short* __restrict__ Qp, const unsigned short* __restrict__ Kp,
    const unsigned short* __restrict__ Vt, const int* __restrict__ mask,
    unsigned short* __restrict__ O) {
  const int bh = blockIdx.y, b_i = bh >> 4, h_i = bh & 15;
  const int q0 = blockIdx.x * 128;
  const int tid = threadIdx.x, wave = tid >> 6, lane = tid & 63;
  const unsigned short* Qb = Qp + (size_t)bh * 65536;
  const unsigned short* Kb = Kp + (size_t)bh * 65536;
  const unsigned short* Vb = Vt + (size_t)bh * 65536;
  const int* maskb = mask + (size_t)b_i * 1048576;

  __shared__ unsigned short Ksm[128 * 64];   // [kpos][d]
  __shared__ unsigned short Vsm[64 * 128];   // [d][kpos]  (V transposed)
  __shared__ unsigned short Psm[4][32 * 128];// per-wave [q][kpos]

  const int fr = lane & 15, fk = (lane >> 4) * 8;
  const int qw = q0 + wave * 32;

  short8 qf[2][2];
#pragma unroll
  for (int mt = 0; mt < 2; ++mt)
#pragma unroll
    for (int ks = 0; ks < 2; ++ks)
      qf[mt][ks] = *(const short8*)&Qb[(size_t)(qw + mt * 16 + fr) * 64 + ks * 32 + fk];

  f32x4 o_acc[2][4] = {};
  float m_run[2][4], l_run[2][4];
#pragma unroll
  for (int mt = 0; mt < 2; ++mt)
#pragma unroll
    for (int r = 0; r < 4; ++r) { m_run[mt][r] = -1e30f; l_run[mt][r] = 0.f; }

  const int kld_row = lane >> 3, kld_col = (lane & 7) * 8;  // K staging (row=128B)
  const int vld_row = lane >> 4, vld_col = (lane & 15) * 8; // Vt staging (row=256B)

  for (int kt = 0; kt < 1024; kt += 128) {
#pragma unroll
    for (int j = 0; j < 4; ++j) {
      const int c = j * 4 + wave;
      gld_lds16(Kb + (size_t)(kt + 8 * c + kld_row) * 64 + kld_col, &Ksm[c * 512]);
      gld_lds16(Vb + (size_t)(4 * c + vld_row) * 1024 + kt + vld_col, &Vsm[c * 512]);
    }
    __syncthreads();

    // S = Q K^T  (per wave: 32 q-rows x 128 k-cols)
    f32x4 s_acc[2][8] = {};
#pragma unroll
    for (int ks = 0; ks < 2; ++ks) {
      short8 kf[8];
#pragma unroll
      for (int nt = 0; nt < 8; ++nt)
        kf[nt] = *(const short8*)&Ksm[(nt * 16 + fr) * 64 + ks * 32 + fk];
#pragma unroll
      for (int mt = 0; mt < 2; ++mt)
#pragma unroll
        for (int nt = 0; nt < 8; ++nt)
          s_acc[mt][nt] = __builtin_amdgcn_mfma_f32_16x16x32_bf16(qf[mt][ks], kf[nt], s_acc[mt][nt], 0, 0, 0);
    }

    // scale + mask + online softmax + write P to per-wave LDS tile
#pragma unroll
    for (int mt = 0; mt < 2; ++mt) {
      const int qrow_b = qw + mt * 16 + (lane >> 4) * 4;
#pragma unroll
      for (int r = 0; r < 4; ++r) {
        const int qrow = qrow_b + r;
        const int moff = qrow * 1024 + kt + fr;
        float sv[8];
#pragma unroll
        for (int nt = 0; nt < 8; ++nt) {
          float s = s_acc[mt][nt][r] * 0.125f;
          if (maskb[moff + nt * 16]) s = -10000.0f;
          sv[nt] = s;
        }
        float mx = sv[0];
#pragma unroll
        for (int nt = 1; nt < 8; ++nt) mx = fmaxf(mx, sv[nt]);
#pragma unroll
        for (int off = 1; off < 16; off <<= 1) mx = fmaxf(mx, __shfl_xor(mx, off, 16));
        const float m_new = fmaxf(m_run[mt][r], mx);
        const float alpha = __expf(m_run[mt][r] - m_new);
        float psum = 0.f;
#pragma unroll
        for (int nt = 0; nt < 8; ++nt) {
          const float p = __expf(sv[nt] - m_new);
          psum += p;
          Psm[wave][(mt * 16 + (lane >> 4) * 4 + r) * 128 + nt * 16 + fr] = f2bf(p);
        }
#pragma unroll
        for (int off = 1; off < 16; off <<= 1) psum += __shfl_xor(psum, off, 16);
        l_run[mt][r] = l_run[mt][r] * alpha + psum;
        m_run[mt][r] = m_new;
#pragma unroll
        for (int dt = 0; dt < 4; ++dt) o_acc[mt][dt][r] *= alpha;
      }
    }

    // O += P V   (A-frags from Psm, B-frags from Vsm)
#pragma unroll
    for (int ks2 = 0; ks2 < 4; ++ks2) {
      short8 vf[4], pf[2];
#pragma unroll
      for (int dt = 0; dt < 4; ++dt)
        vf[dt] = *(const short8*)&Vsm[(dt * 16 + fr) * 128 + ks2 * 32 + fk];
#pragma unroll
      for (int mt = 0; mt < 2; ++mt)
        pf[mt] = *(const short8*)&Psm[wave][(mt * 16 + fr) * 128 + ks2 * 32 + fk];
#pragma unroll
      for (int mt = 0; mt < 2; ++mt)
#pragma unroll
        for (int dt = 0; dt < 4; ++dt)
          o_acc[mt][dt] = __builtin_amdgcn_mfma_f32_16x16x32_bf16(pf[mt], vf[dt], o_acc[mt][dt], 0, 0, 0);
    }
    __syncthreads();
  }

  // normalize + write O as (b,t,f) bf16
#pragma unroll
  for (int mt = 0; mt < 2; ++mt)
#pragma unroll
    for (int r = 0; r < 4; ++r) {
      const int qrow = qw + mt * 16 + (lane >> 4) * 4 + r;
      const float inv_l = 1.0f / l_run[mt][r];
#pragma unroll
      for (int dt = 0; dt < 4; ++dt) {
        const int dcol = dt * 16 + fr;
        O[((size_t)(b_i * 1024 + qrow)) * 1024 + h_i * 64 + dcol] = f2bf(o_acc[mt][dt][r] * inv_l);
      }
    }
}

extern "C" void kernel_launch(void* const* d_in, const int* in_sizes, int n_in,
                              void* d_out, int out_size, void* d_ws, size_t ws_size,
                              hipStream_t stream) {
  const float* query = (const float*)d_in[0];
  const float* key   = (const float*)d_in[1];
  const float* value = (const float*)d_in[2];
  const float* cosb  = (const float*)d_in[3];
  const float* sinb  = (const float*)d_in[4];
  const int*   mask  = (const int*)d_in[5];
  const float* Wq = (const float*)d_in[6];
  const float* bq = (const float*)d_in[7];
  const float* Wk = (const float*)d_in[8];
  const float* bk = (const float*)d_in[9];
  const float* Wv = (const float*)d_in[10];
  const float* bv = (const float*)d_in[11];
  const float* Wo = (const float*)d_in[12];
  const float* bo = (const float*)d_in[13];
  (void)in_sizes; (void)n_in; (void)out_size; (void)ws_size;

  char* ws = (char*)d_ws;
  const size_t MB = 1024 * 1024;
  unsigned short* q_in = (unsigned short*)(ws);             // 16MB, later reused as attn out
  unsigned short* k_in = (unsigned short*)(ws + 16 * MB);   // 16MB
  unsigned short* v_bf = (unsigned short*)(ws + 32 * MB);   // 16MB
  unsigned short* Qp   = (unsigned short*)(ws + 48 * MB);   // 16MB (b,h,t,d)
  unsigned short* Kp   = (unsigned short*)(ws + 64 * MB);   // 16MB (b,h,t,d)
  unsigned short* Vt   = (unsigned short*)(ws + 80 * MB);   // 16MB (b,h,d,t)
  unsigned short* Wqb  = (unsigned short*)(ws + 96 * MB);   // 2MB each
  unsigned short* Wkb  = (unsigned short*)(ws + 98 * MB);
  unsigned short* Wvb  = (unsigned short*)(ws + 100 * MB);
  unsigned short* Wob  = (unsigned short*)(ws + 102 * MB);
  unsigned short* attn = q_in;                              // alias: q_in dead after Q GEMM

  rope_kernel<<<4096, 256, 0, stream>>>(query, key, cosb, sinb, q_in, k_in);
  cast_kernel<<<8192, 256, 0, stream>>>(value, v_bf, 2097152);
  cast_kernel<<<1024, 256, 0, stream>>>(Wq, Wqb, 262144);
  cast_kernel<<<1024, 256, 0, stream>>>(Wk, Wkb, 262144);
  cast_kernel<<<1024, 256, 0, stream>>>(Wv, Wvb, 262144);
  cast_kernel<<<1024, 256, 0, stream>>>(Wo, Wob, 262144);

  dim3 g(64, 8), blk(256);
  gemm_bt<1><<<g, blk, 0, stream>>>(q_in, Wqb, bq, Qp);
  gemm_bt<1><<<g, blk, 0, stream>>>(k_in, Wkb, bk, Kp);
  gemm_bt<2><<<g, blk, 0, stream>>>(v_bf, Wvb, bv, Vt);
  flash_attn<<<dim3(8, 128), blk, 0, stream>>>(Qp, Kp, Vt, mask, attn);
  gemm_bt<0><<<g, blk, 0, stream>>>(attn, Wob, bo, d_out);
}

// Round 2
// 570.131 us; speedup vs baseline: 1.0828x; 1.0828x over previous
//
#include <hip/hip_runtime.h>
#include <stdint.h>

typedef short short8 __attribute__((ext_vector_type(8)));
typedef float f32x4 __attribute__((ext_vector_type(4)));
typedef unsigned short ushort4v __attribute__((ext_vector_type(4)));
typedef unsigned long long u64;

// f32 -> bf16 round-to-nearest-even
__device__ __forceinline__ unsigned short f2bf(float f) {
  union { float f; unsigned u; } v; v.f = f;
  unsigned r = v.u + 0x7fffu + ((v.u >> 16) & 1u);
  return (unsigned short)(r >> 16);
}

// async global->LDS, 16B per lane; lds dst must be wave-uniform (lane*16 auto)
__device__ __forceinline__ void gld_lds16(const void* g, void* l) {
  __builtin_amdgcn_global_load_lds((const __attribute__((address_space(1))) void*)g,
                                   (__attribute__((address_space(3))) void*)l, 16, 0, 0);
}

// ---------------- mask -> bit pack ----------------
// wave w packs mask[w*64 .. w*64+63] into bits[w]. 8M ints -> 1MB of bits.
__global__ void mask_pack(const int* __restrict__ mask, u64* __restrict__ bits) {
  const int tid = blockIdx.x * 256 + threadIdx.x;
  const int w = tid >> 6, lane = tid & 63;
  const int v = mask[(size_t)w * 64 + lane];
  const u64 b = __ballot(v != 0);
  if (lane == 0) bits[w] = b;
}

// ---------------- RoPE + cast to bf16 (query,key) ----------------
__global__ void rope_kernel(const float* __restrict__ q, const float* __restrict__ k,
                            const float* __restrict__ cs, const float* __restrict__ sn,
                            unsigned short* __restrict__ qo, unsigned short* __restrict__ ko) {
  const int idx = blockIdx.x * 256 + threadIdx.x;
  const int p   = idx & 7;
  const int bth = idx >> 3;
  const int t   = (bth >> 4) & 1023;
  const size_t base = (size_t)bth * 64;
  const int dd0 = p * 4;

  const float4 x0 = *(const float4*)(q + base + dd0);
  const float4 x1 = *(const float4*)(q + base + dd0 + 32);
  const float4 y0 = *(const float4*)(k + base + dd0);
  const float4 y1 = *(const float4*)(k + base + dd0 + 32);
  const float4 c0 = *(const float4*)(cs + t * 64 + dd0);
  const float4 c1 = *(const float4*)(cs + t * 64 + dd0 + 32);
  const float4 s0 = *(const float4*)(sn + t * 64 + dd0);
  const float4 s1 = *(const float4*)(sn + t * 64 + dd0 + 32);

  ushort4v qlo, qhi, klo, khi;
  qlo[0]=f2bf(x0.x*c0.x - x1.x*s0.x); qlo[1]=f2bf(x0.y*c0.y - x1.y*s0.y);
  qlo[2]=f2bf(x0.z*c0.z - x1.z*s0.z); qlo[3]=f2bf(x0.w*c0.w - x1.w*s0.w);
  qhi[0]=f2bf(x1.x*c1.x + x0.x*s1.x); qhi[1]=f2bf(x1.y*c1.y + x0.y*s1.y);
  qhi[2]=f2bf(x1.z*c1.z + x0.z*s1.z); qhi[3]=f2bf(x1.w*c1.w + x0.w*s1.w);
  klo[0]=f2bf(y0.x*c0.x - y1.x*s0.x); klo[1]=f2bf(y0.y*c0.y - y1.y*s0.y);
  klo[2]=f2bf(y0.z*c0.z - y1.z*s0.z); klo[3]=f2bf(y0.w*c0.w - y1.w*s0.w);
  khi[0]=f2bf(y1.x*c1.x + y0.x*s1.x); khi[1]=f2bf(y1.y*c1.y + y0.y*s1.y);
  khi[2]=f2bf(y1.z*c1.z + y0.z*s1.z); khi[3]=f2bf(y1.w*c1.w + y0.w*s1.w);

  *(ushort4v*)(qo + base + dd0)      = qlo;
  *(ushort4v*)(qo + base + dd0 + 32) = qhi;
  *(ushort4v*)(ko + base + dd0)      = klo;
  *(ushort4v*)(ko + base + dd0 + 32) = khi;
}

// ---------------- plain f32 -> bf16 cast ----------------
__global__ void cast_kernel(const float* __restrict__ src, unsigned short* __restrict__ dst, int n4) {
  const int i = blockIdx.x * 256 + threadIdx.x;
  if (i < n4) {
    const float4 v = *(const float4*)(src + (size_t)i * 4);
    ushort4v o;
    o[0]=f2bf(v.x); o[1]=f2bf(v.y); o[2]=f2bf(v.z); o[3]=f2bf(v.w);
    *(ushort4v*)(dst + (size_t)i * 4) = o;
  }
}

// ---------------- bf16 GEMM, C[m,n] = sum_k A[m,k]*B[n,k] + bias[n] ----------------
template <int MODE>
__global__ __launch_bounds__(256, 2) void gemm_bt(
    const unsigned short* __restrict__ A, const unsigned short* __restrict__ Bw,
    const float* __restrict__ bias, void* __restrict__ C) {
  constexpr int K = 1024, N = 1024;
  const int tid = threadIdx.x;
  const int wave = tid >> 6, lane = tid & 63;
  const int m0 = blockIdx.x * 128, n0 = blockIdx.y * 128;
  __shared__ unsigned short Asm[128 * 64];
  __shared__ unsigned short Bsm[128 * 64];
  f32x4 acc[4][4] = {};
  const int wr = (wave >> 1) * 64, wc = (wave & 1) * 64;
  const int ld_row = lane >> 3, ld_col = (lane & 7) * 8;
  const int fr = lane & 15, fk = (lane >> 4) * 8;

  for (int k0 = 0; k0 < K; k0 += 64) {
#pragma unroll
    for (int j = 0; j < 4; ++j) {
      const int c = j * 4 + wave;
      gld_lds16(A  + (size_t)(m0 + 8 * c + ld_row) * K + k0 + ld_col, &Asm[c * 512]);
      gld_lds16(Bw + (size_t)(n0 + 8 * c + ld_row) * K + k0 + ld_col, &Bsm[c * 512]);
    }
    __syncthreads();
#pragma unroll
    for (int ks = 0; ks < 2; ++ks) {
      short8 af[4], bf[4];
#pragma unroll
      for (int i = 0; i < 4; ++i)
        af[i] = *(const short8*)&Asm[(wr + i * 16 + fr) * 64 + ks * 32 + fk];
#pragma unroll
      for (int i = 0; i < 4; ++i)
        bf[i] = *(const short8*)&Bsm[(wc + i * 16 + fr) * 64 + ks * 32 + fk];
#pragma unroll
      for (int i = 0; i < 4; ++i)
#pragma unroll
        for (int j = 0; j < 4; ++j)
          acc[i][j] = __builtin_amdgcn_mfma_f32_16x16x32_bf16(af[i], bf[j], acc[i][j], 0, 0, 0);
    }
    __syncthreads();
  }

#pragma unroll
  for (int i = 0; i < 4; ++i) {
    const int row_base = m0 + wr + i * 16 + (lane >> 4) * 4;
#pragma unroll
    for (int j = 0; j < 4; ++j) {
      const int col = n0 + wc + j * 16 + fr;
      const float bval = bias[col];
      if (MODE == 0) {
        float* Co = (float*)C;
#pragma unroll
        for (int r = 0; r < 4; ++r)
          Co[(size_t)(row_base + r) * N + col] = acc[i][j][r] + bval;
      } else if (MODE == 1) {
        unsigned short* Co = (unsigned short*)C;
        const int h_i = col >> 6, dd = col & 63;
#pragma unroll
        for (int r = 0; r < 4; ++r) {
          const int row = row_base + r;
          const int b_i = row >> 10, t_i = row & 1023;
          Co[((size_t)(b_i * 16 + h_i) * 1024 + t_i) * 64 + dd] = f2bf(acc[i][j][r] + bval);
        }
      } else {
        unsigned short* Co = (unsigned short*)C;
        const int h_i = col >> 6, dd = col & 63;
        const int b_i = row_base >> 10, t_i = row_base & 1023;
        ushort4v pk;
        pk[0] = f2bf(acc[i][j][0] + bval); pk[1] = f2bf(acc[i][j][1] + bval);
        pk[2] = f2bf(acc[i][j][2] + bval); pk[3] = f2bf(acc[i][j][3] + bval);
        *(ushort4v*)&Co[((size_t)(b_i * 16 + h_i) * 64 + dd) * 1024 + t_i] = pk;
      }
    }
  }
}

// ---------------- flash attention ----------------
// grid: (8 q-tiles, 128 bh). Q tile 128 rows (32/wave), K/V tiles 128.
// Qp,Kp: (b,h,t,d) bf16. Vt: (b,h,d,t) bf16. mbits: [b][q][k/64] u64. O: (b,t,f) bf16.
// LDS 33280B: Vsm 16K | Ksm 16K overlaid with per-wave P tiles (P written only
// after the post-S barrier, when Ksm is dead). P row stride 132 u16 -> conflict-free writes.
__global__ __launch_bounds__(256, 3) void flash_attn(
    const unsigned short* __restrict__ Qp, const unsigned short* __restrict__ Kp,
    const unsigned short* __restrict__ Vt, const u64* __restrict__ mbits,
    unsigned short* __restrict__ O) {
  const int bh = blockIdx.y, b_i = bh >> 4, h_i = bh & 15;
  const int q0 = blockIdx.x * 128;
  const int tid = threadIdx.x, wave = tid >> 6, lane = tid & 63;
  const unsigned short* Qb = Qp + (size_t)bh * 65536;
  const unsigned short* Kb = Kp + (size_t)bh * 65536;
  const unsigned short* Vb = Vt + (size_t)bh * 65536;
  const u64* mb = mbits + (size_t)b_i * 16384;

  __shared__ unsigned short smem[16640];
  unsigned short* Vsm = smem;                      // [64][128]
  unsigned short* Ksm = smem + 8192;               // [128][64]
  unsigned short* Pw  = smem + 8192 + wave * 2112; // per-wave [16][132]

  const int fr = lane & 15, fk = (lane >> 4) * 8, g = lane >> 4;
  const int qw = q0 + wave * 32;

  short8 qf[2][2];
#pragma unroll
  for (int mt = 0; mt < 2; ++mt)
#pragma unroll
    for (int ks = 0; ks < 2; ++ks)
      qf[mt][ks] = *(const short8*)&Qb[(size_t)(qw + mt * 16 + fr) * 64 + ks * 32 + fk];

  f32x4 o_acc[2][4] = {};
  float m_run[2][4], l_run[2][4];
#pragma unroll
  for (int mt = 0; mt < 2; ++mt)
#pragma unroll
    for (int r = 0; r < 4; ++r) { m_run[mt][r] = -1e30f; l_run[mt][r] = 0.f; }

  const int kld_row = lane >> 3, kld_col = (lane & 7) * 8;
  const int vld_row = lane >> 4, vld_col = (lane & 15) * 8;

  for (int kt = 0; kt < 1024; kt += 128) {
#pragma unroll
    for (int j = 0; j < 4; ++j) {
      const int c = j * 4 + wave;
      gld_lds16(Kb + (size_t)(kt + 8 * c + kld_row) * 64 + kld_col, &Ksm[c * 512]);
      gld_lds16(Vb + (size_t)(4 * c + vld_row) * 1024 + kt + vld_col, &Vsm[c * 512]);
    }
    __syncthreads();

    // S = Q K^T  (per wave: 32 q-rows x 128 k-cols)
    f32x4 s_acc[2][8] = {};
#pragma unroll
    for (int ks = 0; ks < 2; ++ks) {
      short8 kf[8];
#pragma unroll
      for (int nt = 0; nt < 8; ++nt)
        kf[nt] = *(const short8*)&Ksm[(nt * 16 + fr) * 64 + ks * 32 + fk];
#pragma unroll
      for (int mt = 0; mt < 2; ++mt)
#pragma unroll
        for (int nt = 0; nt < 8; ++nt)
          s_acc[mt][nt] = __builtin_amdgcn_mfma_f32_16x16x32_bf16(qf[mt][ks], kf[nt], s_acc[mt][nt], 0, 0, 0);
    }
    __syncthreads();  // Ksm fully consumed -> safe to overlay P

    // per-mt: mask + online softmax (exp2 domain) + P->LDS + PV MFMAs
#pragma unroll
    for (int mt = 0; mt < 2; ++mt) {
#pragma unroll
      for (int r = 0; r < 4; ++r) {
        const int qrow = qw + mt * 16 + g * 4 + r;
        const u64* mrow = &mb[(size_t)qrow * 16 + (kt >> 6)];
        const u64 w0 = mrow[0], w1 = mrow[1];
        float sv[8];
#pragma unroll
        for (int nt = 0; nt < 8; ++nt) {
          float s = s_acc[mt][nt][r] * 0.18033688f;  // 0.125 * log2(e)
          const u64 w = (nt < 4) ? w0 : w1;
          if ((w >> ((nt & 3) * 16 + fr)) & 1) s = -14427.0f;  // -10000 * log2(e)
          sv[nt] = s;
        }
        float mx = sv[0];
#pragma unroll
        for (int nt = 1; nt < 8; ++nt) mx = fmaxf(mx, sv[nt]);
#pragma unroll
        for (int off = 1; off < 16; off <<= 1) mx = fmaxf(mx, __shfl_xor(mx, off, 16));
        const float m_new = fmaxf(m_run[mt][r], mx);
        const float alpha = exp2f(m_run[mt][r] - m_new);
        float psum = 0.f;
#pragma unroll
        for (int nt = 0; nt < 8; ++nt) {
          const float p = exp2f(sv[nt] - m_new);
          psum += p;
          Pw[(g * 4 + r) * 132 + nt * 16 + fr] = f2bf(p);
        }
#pragma unroll
        for (int off = 1; off < 16; off <<= 1) psum += __shfl_xor(psum, off, 16);
        l_run[mt][r] = l_run[mt][r] * alpha + psum;
        m_run[mt][r] = m_new;
#pragma unroll
        for (int dt = 0; dt < 4; ++dt) o_acc[mt][dt][r] *= alpha;
      }

      // O_mt += P_mt V  (A-frags from this wave's private P tile)
#pragma unroll
      for (int ks2 = 0; ks2 < 4; ++ks2) {
        short8 vf[4];
#pragma unroll
        for (int dt = 0; dt < 4; ++dt)
          vf[dt] = *(const short8*)&Vsm[(dt * 16 + fr) * 128 + ks2 * 32 + fk];
        const short8 pf = *(const short8*)&Pw[fr * 132 + ks2 * 32 + fk];
#pragma unroll
        for (int dt = 0; dt < 4; ++dt)
          o_acc[mt][dt] = __builtin_amdgcn_mfma_f32_16x16x32_bf16(pf, vf[dt], o_acc[mt][dt], 0, 0, 0);
      }
    }
    __syncthreads();  // Vsm + P/Ksm region done -> next staging may write
  }

  // normalize + write O as (b,t,f) bf16
#pragma unroll
  for (int mt = 0; mt < 2; ++mt)
#pragma unroll
    for (int r = 0; r < 4; ++r) {
      const int qrow = qw + mt * 16 + g * 4 + r;
      const float inv_l = 1.0f / l_run[mt][r];
#pragma unroll
      for (int dt = 0; dt < 4; ++dt) {
        const int dcol = dt * 16 + fr;
        O[((size_t)(b_i * 1024 + qrow)) * 1024 + h_i * 64 + dcol] = f2bf(o_acc[mt][dt][r] * inv_l);
      }
    }
}

extern "C" void kernel_launch(void* const* d_in, const int* in_sizes, int n_in,
                              void* d_out, int out_size, void* d_ws, size_t ws_size,
                              hipStream_t stream) {
  const float* query = (const float*)d_in[0];
  const float* key   = (const float*)d_in[1];
  const float* value = (const float*)d_in[2];
  const float* cosb  = (const float*)d_in[3];
  const float* sinb  = (const float*)d_in[4];
  const int*   mask  = (const int*)d_in[5];
  const float* Wq = (const float*)d_in[6];
  const float* bq = (const float*)d_in[7];
  const float* Wk = (const float*)d_in[8];
  const float* bk = (const float*)d_in[9];
  const float* Wv = (const float*)d_in[10];
  const float* bv = (const float*)d_in[11];
  const float* Wo = (const float*)d_in[12];
  const float* bo = (const float*)d_in[13];
  (void)in_sizes; (void)n_in; (void)out_size; (void)ws_size;

  char* ws = (char*)d_ws;
  const size_t MB = 1024 * 1024;
  unsigned short* q_in = (unsigned short*)(ws);             // 16MB, later reused as attn out
  unsigned short* k_in = (unsigned short*)(ws + 16 * MB);   // 16MB
  unsigned short* v_bf = (unsigned short*)(ws + 32 * MB);   // 16MB
  unsigned short* Qp   = (unsigned short*)(ws + 48 * MB);   // 16MB (b,h,t,d)
  unsigned short* Kp   = (unsigned short*)(ws + 64 * MB);   // 16MB (b,h,t,d)
  unsigned short* Vt   = (unsigned short*)(ws + 80 * MB);   // 16MB (b,h,d,t)
  unsigned short* Wqb  = (unsigned short*)(ws + 96 * MB);   // 2MB each
  unsigned short* Wkb  = (unsigned short*)(ws + 98 * MB);
  unsigned short* Wvb  = (unsigned short*)(ws + 100 * MB);
  unsigned short* Wob  = (unsigned short*)(ws + 102 * MB);
  u64*            mbits= (u64*)(ws + 104 * MB);             // 1MB
  unsigned short* attn = q_in;                              // alias: q_in dead after Q GEMM

  mask_pack<<<32768, 256, 0, stream>>>(mask, mbits);
  rope_kernel<<<4096, 256, 0, stream>>>(query, key, cosb, sinb, q_in, k_in);
  cast_kernel<<<8192, 256, 0, stream>>>(value, v_bf, 2097152);
  cast_kernel<<<1024, 256, 0, stream>>>(Wq, Wqb, 262144);
  cast_kernel<<<1024, 256, 0, stream>>>(Wk, Wkb, 262144);
  cast_kernel<<<1024, 256, 0, stream>>>(Wv, Wvb, 262144);
  cast_kernel<<<1024, 256, 0, stream>>>(Wo, Wob, 262144);

  dim3 g(64, 8), blk(256);
  gemm_bt<1><<<g, blk, 0, stream>>>(q_in, Wqb, bq, Qp);
  gemm_bt<1><<<g, blk, 0, stream>>>(k_in, Wkb, bk, Kp);
  gemm_bt<2><<<g, blk, 0, stream>>>(v_bf, Wvb, bv, Vt);
  flash_attn<<<dim3(8, 128), blk, 0, stream>>>(Qp, Kp, Vt, mbits, attn);
  gemm_bt<0><<<g, blk, 0, stream>>>(attn, Wob, bo, d_out);
}

// Round 3
// 473.559 us; speedup vs baseline: 1.3036x; 1.2039x over previous
//
#include <hip/hip_runtime.h>
#include <stdint.h>

typedef short short8 __attribute__((ext_vector_type(8)));
typedef float f32x4 __attribute__((ext_vector_type(4)));
typedef unsigned short ushort4v __attribute__((ext_vector_type(4)));
typedef unsigned long long u64;

// f32 -> bf16 round-to-nearest-even
__device__ __forceinline__ unsigned short f2bf(float f) {
  union { float f; unsigned u; } v; v.f = f;
  unsigned r = v.u + 0x7fffu + ((v.u >> 16) & 1u);
  return (unsigned short)(r >> 16);
}

// async global->LDS, 16B per lane; lds dst must be wave-uniform (lane*16 auto)
__device__ __forceinline__ void gld_lds16(const void* g, void* l) {
  __builtin_amdgcn_global_load_lds((const __attribute__((address_space(1))) void*)g,
                                   (__attribute__((address_space(3))) void*)l, 16, 0, 0);
}

// ---------------- mask -> bit pack ----------------
__global__ void mask_pack(const int* __restrict__ mask, u64* __restrict__ bits) {
  const int tid = blockIdx.x * 256 + threadIdx.x;
  const int w = tid >> 6, lane = tid & 63;
  const int v = mask[(size_t)w * 64 + lane];
  const u64 b = __ballot(v != 0);
  if (lane == 0) bits[w] = b;
}

// ---------------- RoPE + cast to bf16 (query,key) ----------------
__global__ void rope_kernel(const float* __restrict__ q, const float* __restrict__ k,
                            const float* __restrict__ cs, const float* __restrict__ sn,
                            unsigned short* __restrict__ qo, unsigned short* __restrict__ ko) {
  const int idx = blockIdx.x * 256 + threadIdx.x;
  const int p   = idx & 7;
  const int bth = idx >> 3;
  const int t   = (bth >> 4) & 1023;
  const size_t base = (size_t)bth * 64;
  const int dd0 = p * 4;

  const float4 x0 = *(const float4*)(q + base + dd0);
  const float4 x1 = *(const float4*)(q + base + dd0 + 32);
  const float4 y0 = *(const float4*)(k + base + dd0);
  const float4 y1 = *(const float4*)(k + base + dd0 + 32);
  const float4 c0 = *(const float4*)(cs + t * 64 + dd0);
  const float4 c1 = *(const float4*)(cs + t * 64 + dd0 + 32);
  const float4 s0 = *(const float4*)(sn + t * 64 + dd0);
  const float4 s1 = *(const float4*)(sn + t * 64 + dd0 + 32);

  ushort4v qlo, qhi, klo, khi;
  qlo[0]=f2bf(x0.x*c0.x - x1.x*s0.x); qlo[1]=f2bf(x0.y*c0.y - x1.y*s0.y);
  qlo[2]=f2bf(x0.z*c0.z - x1.z*s0.z); qlo[3]=f2bf(x0.w*c0.w - x1.w*s0.w);
  qhi[0]=f2bf(x1.x*c1.x + x0.x*s1.x); qhi[1]=f2bf(x1.y*c1.y + x0.y*s1.y);
  qhi[2]=f2bf(x1.z*c1.z + x0.z*s1.z); qhi[3]=f2bf(x1.w*c1.w + x0.w*s1.w);
  klo[0]=f2bf(y0.x*c0.x - y1.x*s0.x); klo[1]=f2bf(y0.y*c0.y - y1.y*s0.y);
  klo[2]=f2bf(y0.z*c0.z - y1.z*s0.z); klo[3]=f2bf(y0.w*c0.w - y1.w*s0.w);
  khi[0]=f2bf(y1.x*c1.x + y0.x*s1.x); khi[1]=f2bf(y1.y*c1.y + y0.y*s1.y);
  khi[2]=f2bf(y1.z*c1.z + y0.z*s1.z); khi[3]=f2bf(y1.w*c1.w + y0.w*s1.w);

  *(ushort4v*)(qo + base + dd0)      = qlo;
  *(ushort4v*)(qo + base + dd0 + 32) = qhi;
  *(ushort4v*)(ko + base + dd0)      = klo;
  *(ushort4v*)(ko + base + dd0 + 32) = khi;
}

// ---------------- plain f32 -> bf16 cast ----------------
__global__ void cast_kernel(const float* __restrict__ src, unsigned short* __restrict__ dst, int n4) {
  const int i = blockIdx.x * 256 + threadIdx.x;
  if (i < n4) {
    const float4 v = *(const float4*)(src + (size_t)i * 4);
    ushort4v o;
    o[0]=f2bf(v.x); o[1]=f2bf(v.y); o[2]=f2bf(v.z); o[3]=f2bf(v.w);
    *(ushort4v*)(dst + (size_t)i * 4) = o;
  }
}

// ---------------- fused 4x weight cast (grid.y selects matrix) ----------------
__global__ void cast4_kernel(const float* __restrict__ s0, const float* __restrict__ s1,
                             const float* __restrict__ s2, const float* __restrict__ s3,
                             unsigned short* __restrict__ d0, unsigned short* __restrict__ d1,
                             unsigned short* __restrict__ d2, unsigned short* __restrict__ d3) {
  const int m = blockIdx.y;
  const float* src = (m == 0) ? s0 : (m == 1) ? s1 : (m == 2) ? s2 : s3;
  unsigned short* dst = (m == 0) ? d0 : (m == 1) ? d1 : (m == 2) ? d2 : d3;
  const int i = blockIdx.x * 256 + threadIdx.x;
  const float4 v = *(const float4*)(src + (size_t)i * 4);
  ushort4v o;
  o[0]=f2bf(v.x); o[1]=f2bf(v.y); o[2]=f2bf(v.z); o[3]=f2bf(v.w);
  *(ushort4v*)(dst + (size_t)i * 4) = o;
}

// ---------------- bf16 GEMM, C[m,n] = sum_k A[m,k]*B[n,k] + bias[n] ----------------
template <int MODE>
__global__ __launch_bounds__(256, 2) void gemm_bt(
    const unsigned short* __restrict__ A, const unsigned short* __restrict__ Bw,
    const float* __restrict__ bias, void* __restrict__ C) {
  constexpr int K = 1024, N = 1024;
  const int tid = threadIdx.x;
  const int wave = tid >> 6, lane = tid & 63;
  const int m0 = blockIdx.x * 128, n0 = blockIdx.y * 128;
  __shared__ unsigned short Asm[128 * 64];
  __shared__ unsigned short Bsm[128 * 64];
  f32x4 acc[4][4] = {};
  const int wr = (wave >> 1) * 64, wc = (wave & 1) * 64;
  const int ld_row = lane >> 3, ld_col = (lane & 7) * 8;
  const int fr = lane & 15, fk = (lane >> 4) * 8;

  for (int k0 = 0; k0 < K; k0 += 64) {
#pragma unroll
    for (int j = 0; j < 4; ++j) {
      const int c = j * 4 + wave;
      gld_lds16(A  + (size_t)(m0 + 8 * c + ld_row) * K + k0 + ld_col, &Asm[c * 512]);
      gld_lds16(Bw + (size_t)(n0 + 8 * c + ld_row) * K + k0 + ld_col, &Bsm[c * 512]);
    }
    __syncthreads();
#pragma unroll
    for (int ks = 0; ks < 2; ++ks) {
      short8 af[4], bf[4];
#pragma unroll
      for (int i = 0; i < 4; ++i)
        af[i] = *(const short8*)&Asm[(wr + i * 16 + fr) * 64 + ks * 32 + fk];
#pragma unroll
      for (int i = 0; i < 4; ++i)
        bf[i] = *(const short8*)&Bsm[(wc + i * 16 + fr) * 64 + ks * 32 + fk];
#pragma unroll
      for (int i = 0; i < 4; ++i)
#pragma unroll
        for (int j = 0; j < 4; ++j)
          acc[i][j] = __builtin_amdgcn_mfma_f32_16x16x32_bf16(af[i], bf[j], acc[i][j], 0, 0, 0);
    }
    __syncthreads();
  }

#pragma unroll
  for (int i = 0; i < 4; ++i) {
    const int row_base = m0 + wr + i * 16 + (lane >> 4) * 4;
#pragma unroll
    for (int j = 0; j < 4; ++j) {
      const int col = n0 + wc + j * 16 + fr;
      const float bval = bias[col];
      if (MODE == 0) {
        float* Co = (float*)C;
#pragma unroll
        for (int r = 0; r < 4; ++r)
          Co[(size_t)(row_base + r) * N + col] = acc[i][j][r] + bval;
      } else if (MODE == 1) {
        unsigned short* Co = (unsigned short*)C;
        const int h_i = col >> 6, dd = col & 63;
#pragma unroll
        for (int r = 0; r < 4; ++r) {
          const int row = row_base + r;
          const int b_i = row >> 10, t_i = row & 1023;
          Co[((size_t)(b_i * 16 + h_i) * 1024 + t_i) * 64 + dd] = f2bf(acc[i][j][r] + bval);
        }
      } else {
        unsigned short* Co = (unsigned short*)C;
        const int h_i = col >> 6, dd = col & 63;
        const int b_i = row_base >> 10, t_i = row_base & 1023;
        ushort4v pk;
        pk[0] = f2bf(acc[i][j][0] + bval); pk[1] = f2bf(acc[i][j][1] + bval);
        pk[2] = f2bf(acc[i][j][2] + bval); pk[3] = f2bf(acc[i][j][3] + bval);
        *(ushort4v*)&Co[((size_t)(b_i * 16 + h_i) * 64 + dd) * 1024 + t_i] = pk;
      }
    }
  }
}

// ---------------- flash attention (no-max softmax: scores bounded, masked -> exact 0) ----------------
// grid: (8 q-tiles, 128 bh). Q tile 128 rows (32/wave), K/V tiles 128.
// Qp,Kp: (b,h,t,d) bf16. Vt: (b,h,d,t) bf16. mbits: [b][q][k/64] u64. O: (b,t,f) bf16.
// LDS 33280B: Vsm 16K | Ksm 16K overlaid with per-wave P tiles (P written only
// after the post-S barrier, when Ksm is dead). P row stride 132 u16 -> conflict-free writes.
__global__ __launch_bounds__(256, 2) void flash_attn(
    const unsigned short* __restrict__ Qp, const unsigned short* __restrict__ Kp,
    const unsigned short* __restrict__ Vt, const u64* __restrict__ mbits,
    unsigned short* __restrict__ O) {
  const int bh = blockIdx.y, b_i = bh >> 4, h_i = bh & 15;
  const int q0 = blockIdx.x * 128;
  const int tid = threadIdx.x, wave = tid >> 6, lane = tid & 63;
  const unsigned short* Qb = Qp + (size_t)bh * 65536;
  const unsigned short* Kb = Kp + (size_t)bh * 65536;
  const unsigned short* Vb = Vt + (size_t)bh * 65536;
  const u64* mb = mbits + (size_t)b_i * 16384;

  __shared__ unsigned short smem[16640];
  unsigned short* Vsm = smem;                      // [64][128]
  unsigned short* Ksm = smem + 8192;               // [128][64]
  unsigned short* Pw  = smem + 8192 + wave * 2112; // per-wave [16][132]

  const int fr = lane & 15, fk = (lane >> 4) * 8, g = lane >> 4;
  const int qw = q0 + wave * 32;

  short8 qf[2][2];
#pragma unroll
  for (int mt = 0; mt < 2; ++mt)
#pragma unroll
    for (int ks = 0; ks < 2; ++ks)
      qf[mt][ks] = *(const short8*)&Qb[(size_t)(qw + mt * 16 + fr) * 64 + ks * 32 + fk];

  f32x4 o_acc[2][4] = {};
  float l_run[2][4] = {};  // per-lane partial row sums (reduced across 16-lane group at end)

  const int kld_row = lane >> 3, kld_col = (lane & 7) * 8;
  const int vld_row = lane >> 4, vld_col = (lane & 15) * 8;

  for (int kt = 0; kt < 1024; kt += 128) {
#pragma unroll
    for (int j = 0; j < 4; ++j) {
      const int c = j * 4 + wave;
      gld_lds16(Kb + (size_t)(kt + 8 * c + kld_row) * 64 + kld_col, &Ksm[c * 512]);
      gld_lds16(Vb + (size_t)(4 * c + vld_row) * 1024 + kt + vld_col, &Vsm[c * 512]);
    }
    __syncthreads();

    // S = Q K^T  (per wave: 32 q-rows x 128 k-cols)
    f32x4 s_acc[2][8] = {};
#pragma unroll
    for (int ks = 0; ks < 2; ++ks) {
      short8 kf[8];
#pragma unroll
      for (int nt = 0; nt < 8; ++nt)
        kf[nt] = *(const short8*)&Ksm[(nt * 16 + fr) * 64 + ks * 32 + fk];
#pragma unroll
      for (int mt = 0; mt < 2; ++mt)
#pragma unroll
        for (int nt = 0; nt < 8; ++nt)
          s_acc[mt][nt] = __builtin_amdgcn_mfma_f32_16x16x32_bf16(qf[mt][ks], kf[nt], s_acc[mt][nt], 0, 0, 0);
    }
    __syncthreads();  // Ksm fully consumed -> safe to overlay P

    // per-mt: mask -> p = exp2(s*scale) (0 if masked), accumulate l, P->LDS, PV MFMAs
#pragma unroll
    for (int mt = 0; mt < 2; ++mt) {
#pragma unroll
      for (int r = 0; r < 4; ++r) {
        const int qrow = qw + mt * 16 + g * 4 + r;
        const u64* mrow = &mb[(size_t)qrow * 16 + (kt >> 6)];
        const u64 w0 = mrow[0], w1 = mrow[1];
        float lp = l_run[mt][r];
#pragma unroll
        for (int nt = 0; nt < 8; ++nt) {
          const u64 w = (nt < 4) ? w0 : w1;
          float p = exp2f(s_acc[mt][nt][r] * 0.18033688f);  // 0.125 * log2(e)
          p = ((w >> ((nt & 3) * 16 + fr)) & 1) ? 0.0f : p;
          lp += p;
          Pw[(g * 4 + r) * 132 + nt * 16 + fr] = f2bf(p);
        }
        l_run[mt][r] = lp;
      }

      // O_mt += P_mt V  (A-frags from this wave's private P tile)
#pragma unroll
      for (int ks2 = 0; ks2 < 4; ++ks2) {
        short8 vf[4];
#pragma unroll
        for (int dt = 0; dt < 4; ++dt)
          vf[dt] = *(const short8*)&Vsm[(dt * 16 + fr) * 128 + ks2 * 32 + fk];
        const short8 pf = *(const short8*)&Pw[fr * 132 + ks2 * 32 + fk];
#pragma unroll
        for (int dt = 0; dt < 4; ++dt)
          o_acc[mt][dt] = __builtin_amdgcn_mfma_f32_16x16x32_bf16(pf, vf[dt], o_acc[mt][dt], 0, 0, 0);
      }
    }
    __syncthreads();  // Vsm + P/Ksm region done -> next staging may write
  }

  // reduce l across the 16-lane group, normalize, write O as (b,t,f) bf16
#pragma unroll
  for (int mt = 0; mt < 2; ++mt)
#pragma unroll
    for (int r = 0; r < 4; ++r) {
      float l = l_run[mt][r];
#pragma unroll
      for (int off = 1; off < 16; off <<= 1) l += __shfl_xor(l, off, 16);
      const float inv_l = 1.0f / l;
      const int qrow = qw + mt * 16 + g * 4 + r;
#pragma unroll
      for (int dt = 0; dt < 4; ++dt) {
        const int dcol = dt * 16 + fr;
        O[((size_t)(b_i * 1024 + qrow)) * 1024 + h_i * 64 + dcol] = f2bf(o_acc[mt][dt][r] * inv_l);
      }
    }
}

extern "C" void kernel_launch(void* const* d_in, const int* in_sizes, int n_in,
                              void* d_out, int out_size, void* d_ws, size_t ws_size,
                              hipStream_t stream) {
  const float* query = (const float*)d_in[0];
  const float* key   = (const float*)d_in[1];
  const float* value = (const float*)d_in[2];
  const float* cosb  = (const float*)d_in[3];
  const float* sinb  = (const float*)d_in[4];
  const int*   mask  = (const int*)d_in[5];
  const float* Wq = (const float*)d_in[6];
  const float* bq = (const float*)d_in[7];
  const float* Wk = (const float*)d_in[8];
  const float* bk = (const float*)d_in[9];
  const float* Wv = (const float*)d_in[10];
  const float* bv = (const float*)d_in[11];
  const float* Wo = (const float*)d_in[12];
  const float* bo = (const float*)d_in[13];
  (void)in_sizes; (void)n_in; (void)out_size; (void)ws_size;

  char* ws = (char*)d_ws;
  const size_t MB = 1024 * 1024;
  unsigned short* q_in = (unsigned short*)(ws);             // 16MB, later reused as attn out
  unsigned short* k_in = (unsigned short*)(ws + 16 * MB);   // 16MB
  unsigned short* v_bf = (unsigned short*)(ws + 32 * MB);   // 16MB
  unsigned short* Qp   = (unsigned short*)(ws + 48 * MB);   // 16MB (b,h,t,d)
  unsigned short* Kp   = (unsigned short*)(ws + 64 * MB);   // 16MB (b,h,t,d)
  unsigned short* Vt   = (unsigned short*)(ws + 80 * MB);   // 16MB (b,h,d,t)
  unsigned short* Wqb  = (unsigned short*)(ws + 96 * MB);   // 2MB each
  unsigned short* Wkb  = (unsigned short*)(ws + 98 * MB);
  unsigned short* Wvb  = (unsigned short*)(ws + 100 * MB);
  unsigned short* Wob  = (unsigned short*)(ws + 102 * MB);
  u64*            mbits= (u64*)(ws + 104 * MB);             // 1MB
  unsigned short* attn = q_in;                              // alias: q_in dead after Q GEMM

  mask_pack<<<32768, 256, 0, stream>>>(mask, mbits);
  rope_kernel<<<4096, 256, 0, stream>>>(query, key, cosb, sinb, q_in, k_in);
  cast_kernel<<<8192, 256, 0, stream>>>(value, v_bf, 2097152);
  cast4_kernel<<<dim3(1024, 4), 256, 0, stream>>>(Wq, Wk, Wv, Wo, Wqb, Wkb, Wvb, Wob);

  dim3 g(64, 8), blk(256);
  gemm_bt<1><<<g, blk, 0, stream>>>(q_in, Wqb, bq, Qp);
  gemm_bt<1><<<g, blk, 0, stream>>>(k_in, Wkb, bk, Kp);
  gemm_bt<2><<<g, blk, 0, stream>>>(v_bf, Wvb, bv, Vt);
  flash_attn<<<dim3(8, 128), blk, 0, stream>>>(Qp, Kp, Vt, mbits, attn);
  gemm_bt<0><<<g, blk, 0, stream>>>(attn, Wob, bo, d_out);
}

// Round 4
// 409.212 us; speedup vs baseline: 1.5086x; 1.1572x over previous
//
#include <hip/hip_runtime.h>
#include <stdint.h>

typedef short short8 __attribute__((ext_vector_type(8)));
typedef float f32x4 __attribute__((ext_vector_type(4)));
typedef unsigned short ushort4v __attribute__((ext_vector_type(4)));
typedef unsigned long long u64;

// f32 -> bf16 round-to-nearest-even
__device__ __forceinline__ unsigned short f2bf(float f) {
  union { float f; unsigned u; } v; v.f = f;
  unsigned r = v.u + 0x7fffu + ((v.u >> 16) & 1u);
  return (unsigned short)(r >> 16);
}

// async global->LDS, 16B per lane; lds dst is wave-uniform base + lane*16
__device__ __forceinline__ void gld_lds16(const void* g, void* l) {
  __builtin_amdgcn_global_load_lds((const __attribute__((address_space(1))) void*)g,
                                   (__attribute__((address_space(3))) void*)l, 16, 0, 0);
}

// ---------------- mask -> bit pack ----------------
__global__ void mask_pack(const int* __restrict__ mask, u64* __restrict__ bits) {
  const int tid = blockIdx.x * 256 + threadIdx.x;
  const int w = tid >> 6, lane = tid & 63;
  const int v = mask[(size_t)w * 64 + lane];
  const u64 b = __ballot(v != 0);
  if (lane == 0) bits[w] = b;
}

// ---------------- RoPE + cast to bf16 (query,key) ----------------
__global__ void rope_kernel(const float* __restrict__ q, const float* __restrict__ k,
                            const float* __restrict__ cs, const float* __restrict__ sn,
                            unsigned short* __restrict__ qo, unsigned short* __restrict__ ko) {
  const int idx = blockIdx.x * 256 + threadIdx.x;
  const int p   = idx & 7;
  const int bth = idx >> 3;
  const int t   = (bth >> 4) & 1023;
  const size_t base = (size_t)bth * 64;
  const int dd0 = p * 4;

  const float4 x0 = *(const float4*)(q + base + dd0);
  const float4 x1 = *(const float4*)(q + base + dd0 + 32);
  const float4 y0 = *(const float4*)(k + base + dd0);
  const float4 y1 = *(const float4*)(k + base + dd0 + 32);
  const float4 c0 = *(const float4*)(cs + t * 64 + dd0);
  const float4 c1 = *(const float4*)(cs + t * 64 + dd0 + 32);
  const float4 s0 = *(const float4*)(sn + t * 64 + dd0);
  const float4 s1 = *(const float4*)(sn + t * 64 + dd0 + 32);

  ushort4v qlo, qhi, klo, khi;
  qlo[0]=f2bf(x0.x*c0.x - x1.x*s0.x); qlo[1]=f2bf(x0.y*c0.y - x1.y*s0.y);
  qlo[2]=f2bf(x0.z*c0.z - x1.z*s0.z); qlo[3]=f2bf(x0.w*c0.w - x1.w*s0.w);
  qhi[0]=f2bf(x1.x*c1.x + x0.x*s1.x); qhi[1]=f2bf(x1.y*c1.y + x0.y*s1.y);
  qhi[2]=f2bf(x1.z*c1.z + x0.z*s1.z); qhi[3]=f2bf(x1.w*c1.w + x0.w*s1.w);
  klo[0]=f2bf(y0.x*c0.x - y1.x*s0.x); klo[1]=f2bf(y0.y*c0.y - y1.y*s0.y);
  klo[2]=f2bf(y0.z*c0.z - y1.z*s0.z); klo[3]=f2bf(y0.w*c0.w - y1.w*s0.w);
  khi[0]=f2bf(y1.x*c1.x + y0.x*s1.x); khi[1]=f2bf(y1.y*c1.y + y0.y*s1.y);
  khi[2]=f2bf(y1.z*c1.z + y0.z*s1.z); khi[3]=f2bf(y1.w*c1.w + y0.w*s1.w);

  *(ushort4v*)(qo + base + dd0)      = qlo;
  *(ushort4v*)(qo + base + dd0 + 32) = qhi;
  *(ushort4v*)(ko + base + dd0)      = klo;
  *(ushort4v*)(ko + base + dd0 + 32) = khi;
}

// ---------------- plain f32 -> bf16 cast ----------------
__global__ void cast_kernel(const float* __restrict__ src, unsigned short* __restrict__ dst, int n4) {
  const int i = blockIdx.x * 256 + threadIdx.x;
  if (i < n4) {
    const float4 v = *(const float4*)(src + (size_t)i * 4);
    ushort4v o;
    o[0]=f2bf(v.x); o[1]=f2bf(v.y); o[2]=f2bf(v.z); o[3]=f2bf(v.w);
    *(ushort4v*)(dst + (size_t)i * 4) = o;
  }
}

// ---------------- fused 4x weight cast ----------------
__global__ void cast4_kernel(const float* __restrict__ s0, const float* __restrict__ s1,
                             const float* __restrict__ s2, const float* __restrict__ s3,
                             unsigned short* __restrict__ d0, unsigned short* __restrict__ d1,
                             unsigned short* __restrict__ d2, unsigned short* __restrict__ d3) {
  const int m = blockIdx.y;
  const float* src = (m == 0) ? s0 : (m == 1) ? s1 : (m == 2) ? s2 : s3;
  unsigned short* dst = (m == 0) ? d0 : (m == 1) ? d1 : (m == 2) ? d2 : d3;
  const int i = blockIdx.x * 256 + threadIdx.x;
  const float4 v = *(const float4*)(src + (size_t)i * 4);
  ushort4v o;
  o[0]=f2bf(v.x); o[1]=f2bf(v.y); o[2]=f2bf(v.z); o[3]=f2bf(v.w);
  *(ushort4v*)(dst + (size_t)i * 4) = o;
}

// ---------------- bf16 GEMM, C[m,n] = sum_k A[m,k]*B[n,k] + bias[n] ----------------
// LDS tiles XOR-swizzled: 16B chunk c of row r stored at position c ^ (r & 7).
// Staging permutes which global chunk each lane fetches (same cache lines);
// fragment reads apply the same XOR -> 2-way max bank aliasing (free).
template <int MODE>
__global__ __launch_bounds__(256, 2) void gemm_bt(
    const unsigned short* __restrict__ A, const unsigned short* __restrict__ Bw,
    const float* __restrict__ bias, void* __restrict__ C) {
  constexpr int K = 1024, N = 1024;
  const int tid = threadIdx.x;
  const int wave = tid >> 6, lane = tid & 63;
  const int m0 = blockIdx.x * 128, n0 = blockIdx.y * 128;
  __shared__ unsigned short Asm[128 * 64];
  __shared__ unsigned short Bsm[128 * 64];
  f32x4 acc[4][4] = {};
  const int wr = (wave >> 1) * 64, wc = (wave & 1) * 64;
  const int ld_row = lane >> 3;
  const int ld_col = ((lane & 7) ^ ld_row) * 8;       // swizzled fetch chunk
  const int fr = lane & 15, g = lane >> 4;
  const int fr7 = fr & 7;

  for (int k0 = 0; k0 < K; k0 += 64) {
#pragma unroll
    for (int j = 0; j < 4; ++j) {
      const int c = j * 4 + wave;
      gld_lds16(A  + (size_t)(m0 + 8 * c + ld_row) * K + k0 + ld_col, &Asm[c * 512]);
      gld_lds16(Bw + (size_t)(n0 + 8 * c + ld_row) * K + k0 + ld_col, &Bsm[c * 512]);
    }
    __syncthreads();
#pragma unroll
    for (int ks = 0; ks < 2; ++ks) {
      const int ch = ((ks * 4 + g) ^ fr7) * 8;        // swizzled fragment chunk
      short8 af[4], bf[4];
#pragma unroll
      for (int i = 0; i < 4; ++i)
        af[i] = *(const short8*)&Asm[(wr + i * 16 + fr) * 64 + ch];
#pragma unroll
      for (int i = 0; i < 4; ++i)
        bf[i] = *(const short8*)&Bsm[(wc + i * 16 + fr) * 64 + ch];
#pragma unroll
      for (int i = 0; i < 4; ++i)
#pragma unroll
        for (int j = 0; j < 4; ++j)
          acc[i][j] = __builtin_amdgcn_mfma_f32_16x16x32_bf16(af[i], bf[j], acc[i][j], 0, 0, 0);
    }
    __syncthreads();
  }

#pragma unroll
  for (int i = 0; i < 4; ++i) {
    const int row_base = m0 + wr + i * 16 + g * 4;
#pragma unroll
    for (int j = 0; j < 4; ++j) {
      const int col = n0 + wc + j * 16 + fr;
      const float bval = bias[col];
      if (MODE == 0) {
        float* Co = (float*)C;
#pragma unroll
        for (int r = 0; r < 4; ++r)
          Co[(size_t)(row_base + r) * N + col] = acc[i][j][r] + bval;
      } else if (MODE == 1) {
        unsigned short* Co = (unsigned short*)C;
        const int h_i = col >> 6, dd = col & 63;
#pragma unroll
        for (int r = 0; r < 4; ++r) {
          const int row = row_base + r;
          const int b_i = row >> 10, t_i = row & 1023;
          Co[((size_t)(b_i * 16 + h_i) * 1024 + t_i) * 64 + dd] = f2bf(acc[i][j][r] + bval);
        }
      } else {
        unsigned short* Co = (unsigned short*)C;
        const int h_i = col >> 6, dd = col & 63;
        const int b_i = row_base >> 10, t_i = row_base & 1023;
        ushort4v pk;
        pk[0] = f2bf(acc[i][j][0] + bval); pk[1] = f2bf(acc[i][j][1] + bval);
        pk[2] = f2bf(acc[i][j][2] + bval); pk[3] = f2bf(acc[i][j][3] + bval);
        *(ushort4v*)&Co[((size_t)(b_i * 16 + h_i) * 64 + dd) * 1024 + t_i] = pk;
      }
    }
  }
}

// ---------------- flash attention (no-max softmax) ----------------
// 1-D grid 1024: bh = id & 127, qt = id >> 7  -> all q-tiles of one bh keep
// id%8 constant -> same XCD -> K/V L2 reuse. Ksm/Vsm XOR-swizzled like gemm.
__global__ __launch_bounds__(256, 2) void flash_attn(
    const unsigned short* __restrict__ Qp, const unsigned short* __restrict__ Kp,
    const unsigned short* __restrict__ Vt, const u64* __restrict__ mbits,
    unsigned short* __restrict__ O) {
  const int bh = blockIdx.x & 127, b_i = bh >> 4, h_i = bh & 15;
  const int q0 = (blockIdx.x >> 7) * 128;
  const int tid = threadIdx.x, wave = tid >> 6, lane = tid & 63;
  const unsigned short* Qb = Qp + (size_t)bh * 65536;
  const unsigned short* Kb = Kp + (size_t)bh * 65536;
  const unsigned short* Vb = Vt + (size_t)bh * 65536;
  const u64* mb = mbits + (size_t)b_i * 16384;

  __shared__ unsigned short smem[16640];
  unsigned short* Vsm = smem;                      // [64][128] swizzled
  unsigned short* Ksm = smem + 8192;               // [128][64] swizzled
  unsigned short* Pw  = smem + 8192 + wave * 2112; // per-wave [16][132]

  const int fr = lane & 15, g = lane >> 4, fr7 = fr & 7;
  const int qw = q0 + wave * 32;

  short8 qf[2][2];
#pragma unroll
  for (int mt = 0; mt < 2; ++mt)
#pragma unroll
    for (int ks = 0; ks < 2; ++ks)
      qf[mt][ks] = *(const short8*)&Qb[(size_t)(qw + mt * 16 + fr) * 64 + ks * 32 + g * 8];

  f32x4 o_acc[2][4] = {};
  float l_run[2][4] = {};

  const int kld_row = lane >> 3;
  const int kld_col = ((lane & 7) ^ kld_row) * 8;                  // K swizzled fetch
  const int vld_row = lane >> 4;
  const int vld_r7w = 4 * (wave & 1) + vld_row;                    // (row&7) for V staging
  const int vld_col = ((lane & 15) ^ vld_r7w) * 8;                 // V swizzled fetch

  for (int kt = 0; kt < 1024; kt += 128) {
#pragma unroll
    for (int j = 0; j < 4; ++j) {
      const int c = j * 4 + wave;
      gld_lds16(Kb + (size_t)(kt + 8 * c + kld_row) * 64 + kld_col, &Ksm[c * 512]);
      gld_lds16(Vb + (size_t)(4 * c + vld_row) * 1024 + kt + vld_col, &Vsm[c * 512]);
    }
    __syncthreads();

    // S = Q K^T  (per wave: 32 q-rows x 128 k-cols)
    f32x4 s_acc[2][8] = {};
#pragma unroll
    for (int ks = 0; ks < 2; ++ks) {
      const int ch = ((ks * 4 + g) ^ fr7) * 8;
      short8 kf[8];
#pragma unroll
      for (int nt = 0; nt < 8; ++nt)
        kf[nt] = *(const short8*)&Ksm[(nt * 16 + fr) * 64 + ch];
#pragma unroll
      for (int mt = 0; mt < 2; ++mt)
#pragma unroll
        for (int nt = 0; nt < 8; ++nt)
          s_acc[mt][nt] = __builtin_amdgcn_mfma_f32_16x16x32_bf16(qf[mt][ks], kf[nt], s_acc[mt][nt], 0, 0, 0);
    }
    __syncthreads();  // Ksm fully consumed -> safe to overlay P

    // per-mt: mask -> p = exp2(s*scale) (0 if masked), accumulate l, P->LDS, PV MFMAs
#pragma unroll
    for (int mt = 0; mt < 2; ++mt) {
#pragma unroll
      for (int r = 0; r < 4; ++r) {
        const int qrow = qw + mt * 16 + g * 4 + r;
        const u64* mrow = &mb[(size_t)qrow * 16 + (kt >> 6)];
        const u64 w0 = mrow[0], w1 = mrow[1];
        float lp = l_run[mt][r];
#pragma unroll
        for (int nt = 0; nt < 8; ++nt) {
          const u64 w = (nt < 4) ? w0 : w1;
          float p = exp2f(s_acc[mt][nt][r] * 0.18033688f);  // 0.125 * log2(e)
          p = ((w >> ((nt & 3) * 16 + fr)) & 1) ? 0.0f : p;
          lp += p;
          Pw[(g * 4 + r) * 132 + nt * 16 + fr] = f2bf(p);
        }
        l_run[mt][r] = lp;
      }

      // O_mt += P_mt V
#pragma unroll
      for (int ks2 = 0; ks2 < 4; ++ks2) {
        const int vch = ((ks2 * 4 + g) ^ fr7) * 8;
        short8 vf[4];
#pragma unroll
        for (int dt = 0; dt < 4; ++dt)
          vf[dt] = *(const short8*)&Vsm[(dt * 16 + fr) * 128 + vch];
        const short8 pf = *(const short8*)&Pw[fr * 132 + ks2 * 32 + g * 8];
#pragma unroll
        for (int dt = 0; dt < 4; ++dt)
          o_acc[mt][dt] = __builtin_amdgcn_mfma_f32_16x16x32_bf16(pf, vf[dt], o_acc[mt][dt], 0, 0, 0);
      }
    }
    __syncthreads();
  }

  // reduce l across the 16-lane group, normalize, write O as (b,t,f) bf16
#pragma unroll
  for (int mt = 0; mt < 2; ++mt)
#pragma unroll
    for (int r = 0; r < 4; ++r) {
      float l = l_run[mt][r];
#pragma unroll
      for (int off = 1; off < 16; off <<= 1) l += __shfl_xor(l, off, 16);
      const float inv_l = 1.0f / l;
      const int qrow = qw + mt * 16 + g * 4 + r;
#pragma unroll
      for (int dt = 0; dt < 4; ++dt) {
        const int dcol = dt * 16 + fr;
        O[((size_t)(b_i * 1024 + qrow)) * 1024 + h_i * 64 + dcol] = f2bf(o_acc[mt][dt][r] * inv_l);
      }
    }
}

extern "C" void kernel_launch(void* const* d_in, const int* in_sizes, int n_in,
                              void* d_out, int out_size, void* d_ws, size_t ws_size,
                              hipStream_t stream) {
  const float* query = (const float*)d_in[0];
  const float* key   = (const float*)d_in[1];
  const float* value = (const float*)d_in[2];
  const float* cosb  = (const float*)d_in[3];
  const float* sinb  = (const float*)d_in[4];
  const int*   mask  = (const int*)d_in[5];
  const float* Wq = (const float*)d_in[6];
  const float* bq = (const float*)d_in[7];
  const float* Wk = (const float*)d_in[8];
  const float* bk = (const float*)d_in[9];
  const float* Wv = (const float*)d_in[10];
  const float* bv = (const float*)d_in[11];
  const float* Wo = (const float*)d_in[12];
  const float* bo = (const float*)d_in[13];
  (void)in_sizes; (void)n_in; (void)out_size; (void)ws_size;

  char* ws = (char*)d_ws;
  const size_t MB = 1024 * 1024;
  unsigned short* q_in = (unsigned short*)(ws);
  unsigned short* k_in = (unsigned short*)(ws + 16 * MB);
  unsigned short* v_bf = (unsigned short*)(ws + 32 * MB);
  unsigned short* Qp   = (unsigned short*)(ws + 48 * MB);
  unsigned short* Kp   = (unsigned short*)(ws + 64 * MB);
  unsigned short* Vt   = (unsigned short*)(ws + 80 * MB);
  unsigned short* Wqb  = (unsigned short*)(ws + 96 * MB);
  unsigned short* Wkb  = (unsigned short*)(ws + 98 * MB);
  unsigned short* Wvb  = (unsigned short*)(ws + 100 * MB);
  unsigned short* Wob  = (unsigned short*)(ws + 102 * MB);
  u64*            mbits= (u64*)(ws + 104 * MB);
  unsigned short* attn = q_in;

  mask_pack<<<32768, 256, 0, stream>>>(mask, mbits);
  rope_kernel<<<4096, 256, 0, stream>>>(query, key, cosb, sinb, q_in, k_in);
  cast_kernel<<<8192, 256, 0, stream>>>(value, v_bf, 2097152);
  cast4_kernel<<<dim3(1024, 4), 256, 0, stream>>>(Wq, Wk, Wv, Wo, Wqb, Wkb, Wvb, Wob);

  dim3 g(64, 8), blk(256);
  gemm_bt<1><<<g, blk, 0, stream>>>(q_in, Wqb, bq, Qp);
  gemm_bt<1><<<g, blk, 0, stream>>>(k_in, Wkb, bk, Kp);
  gemm_bt<2><<<g, blk, 0, stream>>>(v_bf, Wvb, bv, Vt);
  flash_attn<<<1024, blk, 0, stream>>>(Qp, Kp, Vt, mbits, attn);
  gemm_bt<0><<<g, blk, 0, stream>>>(attn, Wob, bo, d_out);
}

// Round 5
// 375.423 us; speedup vs baseline: 1.6444x; 1.0900x over previous
//
#include <hip/hip_runtime.h>
#include <stdint.h>

typedef short short8 __attribute__((ext_vector_type(8)));
typedef float f32x4 __attribute__((ext_vector_type(4)));
typedef unsigned short ushort4v __attribute__((ext_vector_type(4)));
typedef unsigned int uint4v __attribute__((ext_vector_type(4)));
typedef unsigned long long u64;

#if __has_builtin(__builtin_amdgcn_exp2f)
#define EXP2(x) __builtin_amdgcn_exp2f(x)
#else
#define EXP2(x) exp2f(x)
#endif

__device__ __forceinline__ unsigned perm_hi16(unsigned hi, unsigned lo) {
#if __has_builtin(__builtin_amdgcn_perm)
  return __builtin_amdgcn_perm(hi, lo, 0x07060302u);
#else
  return (hi & 0xffff0000u) | (lo >> 16);
#endif
}

// f32 -> bf16 round-to-nearest-even
__device__ __forceinline__ unsigned short f2bf(float f) {
  union { float f; unsigned u; } v; v.f = f;
  unsigned r = v.u + 0x7fffu + ((v.u >> 16) & 1u);
  return (unsigned short)(r >> 16);
}

// async global->LDS, 16B per lane; lds dst is wave-uniform base + lane*16
__device__ __forceinline__ void gld_lds16(const void* g, void* l) {
  __builtin_amdgcn_global_load_lds((const __attribute__((address_space(1))) void*)g,
                                   (__attribute__((address_space(3))) void*)l, 16, 0, 0);
}

// ---------------- mask -> k'-permuted bit pack ----------------
// word w = (b*1024+q)*16 + tblock*2 + h. Bit j of word h corresponds to
// k = (j&7)*16 + (j>>3) + h*8  (k' = (k&15)*8 + (k>>4) ordering).
__global__ void mask_pack(const int* __restrict__ mask, u64* __restrict__ bits) {
  const int tid = blockIdx.x * 256 + threadIdx.x;
  const int w = tid >> 6, lane = tid & 63;
  const int h = w & 1, tb = (w >> 1) & 7, bq = w >> 4;
  const int v = mask[(size_t)bq * 1024 + tb * 128 + h * 8 + (lane & 7) * 16 + (lane >> 3)];
  const u64 b = __ballot(v != 0);
  if (lane == 0) bits[w] = b;
}

// ---------------- RoPE + cast to bf16 (query,key) ----------------
__global__ void rope_kernel(const float* __restrict__ q, const float* __restrict__ k,
                            const float* __restrict__ cs, const float* __restrict__ sn,
                            unsigned short* __restrict__ qo, unsigned short* __restrict__ ko) {
  const int idx = blockIdx.x * 256 + threadIdx.x;
  const int p   = idx & 7;
  const int bth = idx >> 3;
  const int t   = (bth >> 4) & 1023;
  const size_t base = (size_t)bth * 64;
  const int dd0 = p * 4;

  const float4 x0 = *(const float4*)(q + base + dd0);
  const float4 x1 = *(const float4*)(q + base + dd0 + 32);
  const float4 y0 = *(const float4*)(k + base + dd0);
  const float4 y1 = *(const float4*)(k + base + dd0 + 32);
  const float4 c0 = *(const float4*)(cs + t * 64 + dd0);
  const float4 c1 = *(const float4*)(cs + t * 64 + dd0 + 32);
  const float4 s0 = *(const float4*)(sn + t * 64 + dd0);
  const float4 s1 = *(const float4*)(sn + t * 64 + dd0 + 32);

  ushort4v qlo, qhi, klo, khi;
  qlo[0]=f2bf(x0.x*c0.x - x1.x*s0.x); qlo[1]=f2bf(x0.y*c0.y - x1.y*s0.y);
  qlo[2]=f2bf(x0.z*c0.z - x1.z*s0.z); qlo[3]=f2bf(x0.w*c0.w - x1.w*s0.w);
  qhi[0]=f2bf(x1.x*c1.x + x0.x*s1.x); qhi[1]=f2bf(x1.y*c1.y + x0.y*s1.y);
  qhi[2]=f2bf(x1.z*c1.z + x0.z*s1.z); qhi[3]=f2bf(x1.w*c1.w + x0.w*s1.w);
  klo[0]=f2bf(y0.x*c0.x - y1.x*s0.x); klo[1]=f2bf(y0.y*c0.y - y1.y*s0.y);
  klo[2]=f2bf(y0.z*c0.z - y1.z*s0.z); klo[3]=f2bf(y0.w*c0.w - y1.w*s0.w);
  khi[0]=f2bf(y1.x*c1.x + y0.x*s1.x); khi[1]=f2bf(y1.y*c1.y + y0.y*s1.y);
  khi[2]=f2bf(y1.z*c1.z + y0.z*s1.z); khi[3]=f2bf(y1.w*c1.w + y0.w*s1.w);

  *(ushort4v*)(qo + base + dd0)      = qlo;
  *(ushort4v*)(qo + base + dd0 + 32) = qhi;
  *(ushort4v*)(ko + base + dd0)      = klo;
  *(ushort4v*)(ko + base + dd0 + 32) = khi;
}

// ---------------- plain f32 -> bf16 cast ----------------
__global__ void cast_kernel(const float* __restrict__ src, unsigned short* __restrict__ dst, int n4) {
  const int i = blockIdx.x * 256 + threadIdx.x;
  if (i < n4) {
    const float4 v = *(const float4*)(src + (size_t)i * 4);
    ushort4v o;
    o[0]=f2bf(v.x); o[1]=f2bf(v.y); o[2]=f2bf(v.z); o[3]=f2bf(v.w);
    *(ushort4v*)(dst + (size_t)i * 4) = o;
  }
}

// ---------------- fused 4x weight cast ----------------
__global__ void cast4_kernel(const float* __restrict__ s0, const float* __restrict__ s1,
                             const float* __restrict__ s2, const float* __restrict__ s3,
                             unsigned short* __restrict__ d0, unsigned short* __restrict__ d1,
                             unsigned short* __restrict__ d2, unsigned short* __restrict__ d3) {
  const int m = blockIdx.y;
  const float* src = (m == 0) ? s0 : (m == 1) ? s1 : (m == 2) ? s2 : s3;
  unsigned short* dst = (m == 0) ? d0 : (m == 1) ? d1 : (m == 2) ? d2 : d3;
  const int i = blockIdx.x * 256 + threadIdx.x;
  const float4 v = *(const float4*)(src + (size_t)i * 4);
  ushort4v o;
  o[0]=f2bf(v.x); o[1]=f2bf(v.y); o[2]=f2bf(v.z); o[3]=f2bf(v.w);
  *(ushort4v*)(dst + (size_t)i * 4) = o;
}

// ---------------- bf16 GEMM, C[m,n] = (sum_k A[m,k]*B[n,k] + bias[n]) * scale ----------------
// MODE 0: f32 row-major. MODE 1: bf16 (b,h,t,d). MODE 2: bf16 (b,h,d,t') with t'
// k-permuted within 128-blocks: k' = (k&15)*8 + (k>>4)  (for flash PV contraction).
template <int MODE>
__global__ __launch_bounds__(256, 2) void gemm_bt(
    const unsigned short* __restrict__ A, const unsigned short* __restrict__ Bw,
    const float* __restrict__ bias, void* __restrict__ C, float scale) {
  constexpr int K = 1024, N = 1024;
  const int tid = threadIdx.x;
  const int wave = tid >> 6, lane = tid & 63;
  const int m0 = blockIdx.x * 128, n0 = blockIdx.y * 128;
  __shared__ unsigned short Asm[128 * 64];
  __shared__ unsigned short Bsm[128 * 64];
  f32x4 acc[4][4] = {};
  const int wr = (wave >> 1) * 64, wc = (wave & 1) * 64;
  const int ld_row = lane >> 3;
  const int ld_col = ((lane & 7) ^ ld_row) * 8;       // swizzled fetch chunk
  const int fr = lane & 15, g = lane >> 4;
  const int fr7 = fr & 7;

  for (int k0 = 0; k0 < K; k0 += 64) {
#pragma unroll
    for (int j = 0; j < 4; ++j) {
      const int c = j * 4 + wave;
      gld_lds16(A  + (size_t)(m0 + 8 * c + ld_row) * K + k0 + ld_col, &Asm[c * 512]);
      gld_lds16(Bw + (size_t)(n0 + 8 * c + ld_row) * K + k0 + ld_col, &Bsm[c * 512]);
    }
    __syncthreads();
#pragma unroll
    for (int ks = 0; ks < 2; ++ks) {
      const int ch = ((ks * 4 + g) ^ fr7) * 8;        // swizzled fragment chunk
      short8 af[4], bf[4];
#pragma unroll
      for (int i = 0; i < 4; ++i)
        af[i] = *(const short8*)&Asm[(wr + i * 16 + fr) * 64 + ch];
#pragma unroll
      for (int i = 0; i < 4; ++i)
        bf[i] = *(const short8*)&Bsm[(wc + i * 16 + fr) * 64 + ch];
#pragma unroll
      for (int i = 0; i < 4; ++i)
#pragma unroll
        for (int j = 0; j < 4; ++j)
          acc[i][j] = __builtin_amdgcn_mfma_f32_16x16x32_bf16(af[i], bf[j], acc[i][j], 0, 0, 0);
    }
    __syncthreads();
  }

#pragma unroll
  for (int i = 0; i < 4; ++i) {
    const int row_base = m0 + wr + i * 16 + g * 4;
#pragma unroll
    for (int j = 0; j < 4; ++j) {
      const int col = n0 + wc + j * 16 + fr;
      const float bval = bias[col];
      if (MODE == 0) {
        float* Co = (float*)C;
#pragma unroll
        for (int r = 0; r < 4; ++r)
          Co[(size_t)(row_base + r) * N + col] = (acc[i][j][r] + bval) * scale;
      } else if (MODE == 1) {
        unsigned short* Co = (unsigned short*)C;
        const int h_i = col >> 6, dd = col & 63;
#pragma unroll
        for (int r = 0; r < 4; ++r) {
          const int row = row_base + r;
          const int b_i = row >> 10, t_i = row & 1023;
          Co[((size_t)(b_i * 16 + h_i) * 1024 + t_i) * 64 + dd] = f2bf((acc[i][j][r] + bval) * scale);
        }
      } else {
        unsigned short* Co = (unsigned short*)C;
        const int h_i = col >> 6, dd = col & 63;
#pragma unroll
        for (int r = 0; r < 4; ++r) {
          const int row = row_base + r;
          const int b_i = row >> 10, t_i = row & 1023;
          const int kp = (t_i & 15) * 8 + ((t_i >> 4) & 7);   // k' within 128-block
          Co[((size_t)(b_i * 16 + h_i) * 64 + dd) * 1024 + (t_i & ~127) + kp] =
              f2bf((acc[i][j][r] + bval) * scale);
        }
      }
    }
  }
}

// ---------------- flash attention (no-max softmax, k'-permuted P/V) ----------------
// Qp pre-scaled by 0.125*log2(e) in its GEMM epilogue -> p = exp2(s_acc) directly.
// P stored k'-permuted: lane's 8 values per (mt,r) are contiguous -> 1 ds_write_b128.
// Vp global layout is k'-permuted to match. Pw overlays Ksm (dead after S), XOR-swizzled.
__global__ __launch_bounds__(256, 2) void flash_attn(
    const unsigned short* __restrict__ Qp, const unsigned short* __restrict__ Kp,
    const unsigned short* __restrict__ Vp, const u64* __restrict__ mbits,
    unsigned short* __restrict__ O) {
  const int bh = blockIdx.x & 127, b_i = bh >> 4, h_i = bh & 15;
  const int q0 = (blockIdx.x >> 7) * 128;
  const int tid = threadIdx.x, wave = tid >> 6, lane = tid & 63;
  const unsigned short* Qb = Qp + (size_t)bh * 65536;
  const unsigned short* Kb = Kp + (size_t)bh * 65536;
  const unsigned short* Vb = Vp + (size_t)bh * 65536;
  const u64* mb = mbits + (size_t)b_i * 16384;

  __shared__ unsigned short smem[16384];
  unsigned short* Vsm = smem;                      // [64][128] swizzled
  unsigned short* Ksm = smem + 8192;               // [128][64] swizzled
  unsigned short* Pw  = smem + 8192 + wave * 2048; // per-wave [16][128] chunk-swizzled

  const int fr = lane & 15, g = lane >> 4, fr7 = fr & 7;
  const int qw = q0 + wave * 32;

  short8 qf[2][2];
#pragma unroll
  for (int mt = 0; mt < 2; ++mt)
#pragma unroll
    for (int ks = 0; ks < 2; ++ks)
      qf[mt][ks] = *(const short8*)&Qb[(size_t)(qw + mt * 16 + fr) * 64 + ks * 32 + g * 8];

  f32x4 o_acc[2][4] = {};
  float l_run[2][4] = {};

  const int kld_row = lane >> 3;
  const int kld_col = ((lane & 7) ^ kld_row) * 8;                  // K swizzled fetch
  const int vld_row = lane >> 4;
  const int vld_r7w = 4 * (wave & 1) + vld_row;                    // (row&7) for V staging
  const int vld_col = ((lane & 15) ^ vld_r7w) * 8;                 // V swizzled fetch

  for (int kt = 0; kt < 1024; kt += 128) {
#pragma unroll
    for (int j = 0; j < 4; ++j) {
      const int c = j * 4 + wave;
      gld_lds16(Kb + (size_t)(kt + 8 * c + kld_row) * 64 + kld_col, &Ksm[c * 512]);
      gld_lds16(Vb + (size_t)(4 * c + vld_row) * 1024 + kt + vld_col, &Vsm[c * 512]);
    }
    __syncthreads();

    // S = Q K^T  (per wave: 32 q-rows x 128 k-cols)
    f32x4 s_acc[2][8] = {};
#pragma unroll
    for (int ks = 0; ks < 2; ++ks) {
      const int ch = ((ks * 4 + g) ^ fr7) * 8;
      short8 kf[8];
#pragma unroll
      for (int nt = 0; nt < 8; ++nt)
        kf[nt] = *(const short8*)&Ksm[(nt * 16 + fr) * 64 + ch];
#pragma unroll
      for (int mt = 0; mt < 2; ++mt)
#pragma unroll
        for (int nt = 0; nt < 8; ++nt)
          s_acc[mt][nt] = __builtin_amdgcn_mfma_f32_16x16x32_bf16(qf[mt][ks], kf[nt], s_acc[mt][nt], 0, 0, 0);
    }
    __syncthreads();  // Ksm fully consumed -> safe to overlay P

#pragma unroll
    for (int mt = 0; mt < 2; ++mt) {
#pragma unroll
      for (int r = 0; r < 4; ++r) {
        const int qrow = qw + mt * 16 + g * 4 + r;
        const u64 w = mb[qrow * 16 + (kt >> 7) * 2 + (fr >> 3)];
        const unsigned byte8 = (unsigned)(w >> ((fr & 7) * 8)) & 0xffu;
        float lp = l_run[mt][r];
        unsigned t8[8];
#pragma unroll
        for (int nt = 0; nt < 8; ++nt) {
          float e = EXP2(s_acc[mt][nt][r]);
          e = (byte8 & (1u << nt)) ? 0.0f : e;
          lp += e;
          union { float f; unsigned u; } cv; cv.f = e;
          t8[nt] = cv.u + 0x7fffu + ((cv.u >> 16) & 1u);
        }
        l_run[mt][r] = lp;
        uint4v pk;
        pk[0] = perm_hi16(t8[1], t8[0]);
        pk[1] = perm_hi16(t8[3], t8[2]);
        pk[2] = perm_hi16(t8[5], t8[4]);
        pk[3] = perm_hi16(t8[7], t8[6]);
        const int prow = g * 4 + r;
        *(uint4v*)&Pw[prow * 128 + ((fr ^ (prow & 7)) * 8)] = pk;
      }

      // O_mt += P_mt V   (contraction in k'-order on both operands)
#pragma unroll
      for (int ks2 = 0; ks2 < 4; ++ks2) {
        const int cc = (ks2 * 4 + g) ^ fr7;
        short8 vf[4];
#pragma unroll
        for (int dt = 0; dt < 4; ++dt)
          vf[dt] = *(const short8*)&Vsm[(dt * 16 + fr) * 128 + cc * 8];
        const short8 pf = *(const short8*)&Pw[fr * 128 + cc * 8];
#pragma unroll
        for (int dt = 0; dt < 4; ++dt)
          o_acc[mt][dt] = __builtin_amdgcn_mfma_f32_16x16x32_bf16(pf, vf[dt], o_acc[mt][dt], 0, 0, 0);
      }
    }
    __syncthreads();
  }

  // reduce l across the 16-lane group, normalize, write O as (b,t,f) bf16
#pragma unroll
  for (int mt = 0; mt < 2; ++mt)
#pragma unroll
    for (int r = 0; r < 4; ++r) {
      float l = l_run[mt][r];
#pragma unroll
      for (int off = 1; off < 16; off <<= 1) l += __shfl_xor(l, off, 16);
      const float inv_l = 1.0f / l;
      const int qrow = qw + mt * 16 + g * 4 + r;
#pragma unroll
      for (int dt = 0; dt < 4; ++dt) {
        const int dcol = dt * 16 + fr;
        O[((size_t)(b_i * 1024 + qrow)) * 1024 + h_i * 64 + dcol] = f2bf(o_acc[mt][dt][r] * inv_l);
      }
    }
}

extern "C" void kernel_launch(void* const* d_in, const int* in_sizes, int n_in,
                              void* d_out, int out_size, void* d_ws, size_t ws_size,
                              hipStream_t stream) {
  const float* query = (const float*)d_in[0];
  const float* key   = (const float*)d_in[1];
  const float* value = (const float*)d_in[2];
  const float* cosb  = (const float*)d_in[3];
  const float* sinb  = (const float*)d_in[4];
  const int*   mask  = (const int*)d_in[5];
  const float* Wq = (const float*)d_in[6];
  const float* bq = (const float*)d_in[7];
  const float* Wk = (const float*)d_in[8];
  const float* bk = (const float*)d_in[9];
  const float* Wv = (const float*)d_in[10];
  const float* bv = (const float*)d_in[11];
  const float* Wo = (const float*)d_in[12];
  const float* bo = (const float*)d_in[13];
  (void)in_sizes; (void)n_in; (void)out_size; (void)ws_size;

  char* ws = (char*)d_ws;
  const size_t MB = 1024 * 1024;
  unsigned short* q_in = (unsigned short*)(ws);
  unsigned short* k_in = (unsigned short*)(ws + 16 * MB);
  unsigned short* v_bf = (unsigned short*)(ws + 32 * MB);
  unsigned short* Qp   = (unsigned short*)(ws + 48 * MB);
  unsigned short* Kp   = (unsigned short*)(ws + 64 * MB);
  unsigned short* Vp   = (unsigned short*)(ws + 80 * MB);
  unsigned short* Wqb  = (unsigned short*)(ws + 96 * MB);
  unsigned short* Wkb  = (unsigned short*)(ws + 98 * MB);
  unsigned short* Wvb  = (unsigned short*)(ws + 100 * MB);
  unsigned short* Wob  = (unsigned short*)(ws + 102 * MB);
  u64*            mbits= (u64*)(ws + 104 * MB);
  unsigned short* attn = q_in;

  mask_pack<<<32768, 256, 0, stream>>>(mask, mbits);
  rope_kernel<<<4096, 256, 0, stream>>>(query, key, cosb, sinb, q_in, k_in);
  cast_kernel<<<8192, 256, 0, stream>>>(value, v_bf, 2097152);
  cast4_kernel<<<dim3(1024, 4), 256, 0, stream>>>(Wq, Wk, Wv, Wo, Wqb, Wkb, Wvb, Wob);

  dim3 g(64, 8), blk(256);
  gemm_bt<1><<<g, blk, 0, stream>>>(q_in, Wqb, bq, Qp, 0.18033688f);  // 0.125*log2(e) folded
  gemm_bt<1><<<g, blk, 0, stream>>>(k_in, Wkb, bk, Kp, 1.0f);
  gemm_bt<2><<<g, blk, 0, stream>>>(v_bf, Wvb, bv, Vp, 1.0f);
  flash_attn<<<1024, blk, 0, stream>>>(Qp, Kp, Vp, mbits, attn);
  gemm_bt<0><<<g, blk, 0, stream>>>(attn, Wob, bo, d_out, 1.0f);
}